// Round 1
// baseline (1296.292 us; speedup 1.0000x reference)
//
#include <hip/hip_runtime.h>

#define VOCAB_ROWS 50001
#define EMB 32
#define UNITS 16
#define GATES 48
#define BATCH 256
#define SEQ 4096

// ---------------- Phase 1: per-vocab projection table ----------------
// proj[v][j] = bias[0][j] + sum_e emb[v][e] * kernel[e][j]
__global__ __launch_bounds__(256) void proj_kernel(const float* __restrict__ emb,
                                                   const float* __restrict__ kern,
                                                   const float* __restrict__ bias,
                                                   float* __restrict__ proj) {
    int gid = blockIdx.x * 256 + threadIdx.x;
    if (gid >= VOCAB_ROWS * GATES) return;
    int v = gid / GATES;
    int j = gid - v * GATES;
    const float* erow = emb + v * EMB;
    float acc = bias[j];
#pragma unroll
    for (int e = 0; e < EMB; ++e)
        acc = fmaf(erow[e], kern[e * GATES + j], acc);
    proj[gid] = acc;
}

// ---------------- Phase 2: sequential GRU scan ----------------
__device__ __forceinline__ float sigf(float x) {
    float e = __expf(-x);
    return __builtin_amdgcn_rcpf(1.0f + e);
}

// One wave (64 lanes) per block; lanes = 4 sub-batches x 16 units.
// Grid = 64 blocks -> 256 batch rows total, 1 wave per CU (full issue BW each).
__global__ __launch_bounds__(64) void gru_scan(const int* __restrict__ ids,
                                               const float* __restrict__ reck,
                                               const float* __restrict__ bias,
                                               const float* __restrict__ proj,
                                               float* __restrict__ out) {
    const int lane = threadIdx.x;     // 0..63
    const int sub  = lane >> 4;       // 0..3
    const int u    = lane & 15;       // unit
    const int b    = blockIdx.x * 4 + sub;
    const int* __restrict__ idrow = ids + (size_t)b * SEQ;

    // recurrent weight columns for this unit (z, r, h gates)
    float Rz[UNITS], Rr[UNITS], Rh[UNITS];
#pragma unroll
    for (int k = 0; k < UNITS; ++k) {
        Rz[k] = reck[k * GATES + u];
        Rr[k] = reck[k * GATES + 16 + u];
        Rh[k] = reck[k * GATES + 32 + u];
    }
    const float bz = bias[GATES + u];
    const float br = bias[GATES + 16 + u];
    const float bh = bias[GATES + 32 + u];

    // software-pipeline rings: x rows 8 ahead, ids 16 ahead
    float xq0[8], xq1[8], xq2[8];
    int   idq[8];
#pragma unroll
    for (int s = 0; s < 8; ++s) {
        int id0 = idrow[s];
        const float* prow = proj + (size_t)id0 * GATES;
        xq0[s] = prow[u];
        xq1[s] = prow[16 + u];
        xq2[s] = prow[32 + u];
        idq[s] = idrow[8 + s];
    }

    float h = 0.0f;
    for (int t0 = 0; t0 < SEQ; t0 += 8) {
#pragma unroll
        for (int uu = 0; uu < 8; ++uu) {
            const int t = t0 + uu;
            // consume row for step t
            const float xz = xq0[uu];
            const float xr = xq1[uu];
            const float xh = xq2[uu];
            // prefetch: gather row for t+8 (id loaded 8 steps ago), load id for t+16
            const int id8 = idq[uu];
            int tf = t + 16;
            tf = tf < SEQ ? tf : SEQ - 1;
            idq[uu] = idrow[tf];
            const float* prow = proj + (size_t)id8 * GATES;
            xq0[uu] = prow[u];
            xq1[uu] = prow[16 + u];
            xq2[uu] = prow[32 + u];

            // broadcast h across the 16-lane group, 16x48 matvec
            float az0 = 0.f, az1 = 0.f;
            float ar0 = 0.f, ar1 = 0.f;
            float ah0 = 0.f, ah1 = 0.f;
#pragma unroll
            for (int k = 0; k < 8; ++k) {
                const float ha = __shfl(h, k, 16);
                const float hb = __shfl(h, k + 8, 16);
                az0 = fmaf(Rz[k], ha, az0);
                az1 = fmaf(Rz[k + 8], hb, az1);
                ar0 = fmaf(Rr[k], ha, ar0);
                ar1 = fmaf(Rr[k + 8], hb, ar1);
                ah0 = fmaf(Rh[k], ha, ah0);
                ah1 = fmaf(Rh[k + 8], hb, ah1);
            }
            const float z  = sigf(xz + bz + az0 + az1);
            const float r  = sigf(xr + br + ar0 + ar1);
            const float rh = bh + ah0 + ah1;
            const float hh = sigf(xh + r * rh);
            h = fmaf(z, h - hh, hh);   // z*h + (1-z)*hh
        }
    }

    out[b * UNITS + u] = h;
}

extern "C" void kernel_launch(void* const* d_in, const int* in_sizes, int n_in,
                              void* d_out, int out_size, void* d_ws, size_t ws_size,
                              hipStream_t stream) {
    const int*   ids  = (const int*)d_in[0];
    const float* emb  = (const float*)d_in[1];
    const float* kern = (const float*)d_in[2];
    const float* reck = (const float*)d_in[3];
    const float* bias = (const float*)d_in[4];
    float* out  = (float*)d_out;
    float* proj = (float*)d_ws;   // 50001*48 floats = 9.6 MB scratch

    const int total = VOCAB_ROWS * GATES;
    proj_kernel<<<(total + 255) / 256, 256, 0, stream>>>(emb, kern, bias, proj);
    gru_scan<<<64, 64, 0, stream>>>(ids, reck, bias, proj, out);
}

// Round 2
// 796.476 us; speedup vs baseline: 1.6275x; 1.6275x over previous
//
#include <hip/hip_runtime.h>

#define VOCAB_ROWS 50001
#define EMB 32
#define UNITS 16
#define GATES 48
#define BATCH 256
#define SEQ 4096

// ---------------- Phase 1: per-vocab projection table ----------------
// proj[v][j] = bias[0][j] + sum_e emb[v][e] * kernel[e][j]
__global__ __launch_bounds__(256) void proj_kernel(const float* __restrict__ emb,
                                                   const float* __restrict__ kern,
                                                   const float* __restrict__ bias,
                                                   float* __restrict__ proj) {
    int gid = blockIdx.x * 256 + threadIdx.x;
    if (gid >= VOCAB_ROWS * GATES) return;
    int v = gid / GATES;
    int j = gid - v * GATES;
    const float* erow = emb + v * EMB;
    float acc = bias[j];
#pragma unroll
    for (int e = 0; e < EMB; ++e)
        acc = fmaf(erow[e], kern[e * GATES + j], acc);
    proj[gid] = acc;
}

// ---------------- Phase 2: sequential GRU scan ----------------
__device__ __forceinline__ float sigf(float x) {
    float e = __expf(-x);
    return __builtin_amdgcn_rcpf(1.0f + e);
}

// Broadcast lane l's value through an SGPR (VALU pipe, no LDS/DS latency).
__device__ __forceinline__ float rdlane(float v, int l) {
    return __int_as_float(__builtin_amdgcn_readlane(__float_as_int(v), l));
}

// ONE batch row per wave; all 64 lanes compute redundantly with u = lane&15.
// h broadcast goes through v_readlane -> SGPR (latency ~5 cyc) instead of
// ds_bpermute (~120 cyc) -- removes the DS pipe from the critical path.
__global__ __launch_bounds__(64) void gru_scan(const int* __restrict__ ids,
                                               const float* __restrict__ reck,
                                               const float* __restrict__ bias,
                                               const float* __restrict__ proj,
                                               float* __restrict__ out) {
    const int lane = threadIdx.x & 63;
    const int u    = lane & 15;          // unit; lanes 16..63 mirror lanes 0..15
    const int b    = blockIdx.x;         // one row per wave
    const int* __restrict__ idrow = ids + (size_t)b * SEQ;

    // recurrent weight columns for this unit (z, r, h gates)
    float Rz[UNITS], Rr[UNITS], Rh[UNITS];
#pragma unroll
    for (int k = 0; k < UNITS; ++k) {
        Rz[k] = reck[k * GATES + u];
        Rr[k] = reck[k * GATES + 16 + u];
        Rh[k] = reck[k * GATES + 32 + u];
    }
    const float bz = bias[GATES + u];
    const float br = bias[GATES + 16 + u];
    const float bh = bias[GATES + 32 + u];

    // software-pipeline rings: x rows 8 ahead, ids 16 ahead
    float xq0[8], xq1[8], xq2[8];
    int   idq[8];
#pragma unroll
    for (int s = 0; s < 8; ++s) {
        int id0 = idrow[s];
        const float* prow = proj + (size_t)id0 * GATES;
        xq0[s] = prow[u];
        xq1[s] = prow[16 + u];
        xq2[s] = prow[32 + u];
        idq[s] = idrow[8 + s];
    }

    float h = 0.0f;
    for (int t0 = 0; t0 < SEQ; t0 += 8) {
#pragma unroll
        for (int uu = 0; uu < 8; ++uu) {
            const int t = t0 + uu;
            // consume row for step t
            const float xz = xq0[uu];
            const float xr = xq1[uu];
            const float xh = xq2[uu];
            // prefetch: gather row for t+8 (id loaded 8 steps ago), id for t+16
            const int id8 = idq[uu];
            int tf = t + 16;
            tf = tf < SEQ ? tf : SEQ - 1;
            idq[uu] = idrow[tf];
            const float* prow = proj + (size_t)id8 * GATES;
            xq0[uu] = prow[u];
            xq1[uu] = prow[16 + u];
            xq2[uu] = prow[32 + u];

            // 16x48 matvec: h broadcast via readlane (SGPR), 6 FMA chains of 8
            float az0 = bz,  az1 = 0.f;
            float ar0 = br,  ar1 = 0.f;
            float ah0 = bh,  ah1 = 0.f;
#pragma unroll
            for (int k = 0; k < 8; ++k) {
                const float ha = rdlane(h, k);
                const float hb = rdlane(h, k + 8);
                az0 = fmaf(Rz[k],     ha, az0);
                az1 = fmaf(Rz[k + 8], hb, az1);
                ar0 = fmaf(Rr[k],     ha, ar0);
                ar1 = fmaf(Rr[k + 8], hb, ar1);
                ah0 = fmaf(Rh[k],     ha, ah0);
                ah1 = fmaf(Rh[k + 8], hb, ah1);
            }
            const float z  = sigf(xz + az0 + az1);
            const float r  = sigf(xr + ar0 + ar1);
            const float rh = ah0 + ah1;
            const float hh = sigf(xh + r * rh);
            h = fmaf(z, h - hh, hh);   // z*h + (1-z)*hh
        }
    }

    if (lane < UNITS) out[b * UNITS + u] = h;
}

extern "C" void kernel_launch(void* const* d_in, const int* in_sizes, int n_in,
                              void* d_out, int out_size, void* d_ws, size_t ws_size,
                              hipStream_t stream) {
    const int*   ids  = (const int*)d_in[0];
    const float* emb  = (const float*)d_in[1];
    const float* kern = (const float*)d_in[2];
    const float* reck = (const float*)d_in[3];
    const float* bias = (const float*)d_in[4];
    float* out  = (float*)d_out;
    float* proj = (float*)d_ws;   // 50001*48 floats = 9.6 MB scratch

    const int total = VOCAB_ROWS * GATES;
    proj_kernel<<<(total + 255) / 256, 256, 0, stream>>>(emb, kern, bias, proj);
    gru_scan<<<BATCH, 64, 0, stream>>>(ids, reck, bias, proj, out);
}